// Round 1
// baseline (161.737 us; speedup 1.0000x reference)
//
#include <hip/hip_runtime.h>

#define NLAYERS 4
#define BATCH   64
#define LEN1    256
#define LEN2    256
#define DIM     1024
#define BKK     64
#define NKT     (DIM / BKK)   // 16 K-tiles

typedef _Float16 f16x8 __attribute__((ext_vector_type(8)));
typedef float    f32x4 __attribute__((ext_vector_type(4)));

// ---------------------------------------------------------------------------
// Kernel 1: one block per (nl, b).  Computes the full 256x256 similarity tile
// with f16 MFMA (unnormalized dots), fp32 row sums-of-squares on the fly,
// applies 1/(||r1_i|| ||r2_j||) scaling in the epilogue, then masked
// max-over-rows / max-over-cols + masked means -> F1 -> feat[b][nl].
// ---------------------------------------------------------------------------
__global__ __launch_bounds__(512, 2)
void bs_main(const float* __restrict__ reps1, const float* __restrict__ reps2,
             const int* __restrict__ len1, const int* __restrict__ len2,
             float* __restrict__ feat) {
  __shared__ _Float16 Ah[LEN1 * BKK];   // 32 KB, XOR-swizzled
  __shared__ _Float16 Bh[LEN2 * BKK];   // 32 KB, XOR-swizzled
  __shared__ float ssq1[LEN1];
  __shared__ float ssq2[LEN2];
  __shared__ float rowp[LEN1][2];       // per-row max partials (indexed by wn)
  __shared__ float colp[LEN2][4];       // per-col max partials (indexed by wm)
  __shared__ float redbuf[16];

  const int bid = blockIdx.x;
  const int nl  = bid / BATCH;
  const int bb  = bid - nl * BATCH;
  const float* gA = reps1 + (size_t)(nl * BATCH + bb) * LEN1 * DIM;
  const float* gB = reps2 + (size_t)(nl * BATCH + bb) * LEN2 * DIM;

  const int tid  = threadIdx.x;
  const int lane = tid & 63;
  const int wid  = tid >> 6;     // 8 waves
  const int wm   = wid >> 1;     // 0..3  (M direction, 64 rows each)
  const int wn   = wid & 1;      // 0..1  (N direction, 128 cols each)
  const int li   = lane & 15;
  const int lh   = lane >> 4;

  if (tid < 256) ssq1[tid] = 0.0f;
  else           ssq2[tid - 256] = 0.0f;

  f32x4 acc[4][8];
  #pragma unroll
  for (int a = 0; a < 4; ++a) {
    #pragma unroll
    for (int c = 0; c < 8; ++c) acc[a][c] = 0.0f;
  }

  float pssqA[4] = {0.f, 0.f, 0.f, 0.f};
  float pssqB[4] = {0.f, 0.f, 0.f, 0.f};
  const int crow = tid >> 3;  // 0..63 : staging row group
  const int cg   = tid & 7;   // 0..7  : 8-float chunk within row

  for (int kt = 0; kt < NKT; ++kt) {
    // ---- load tile kt (global -> regs), 32 floats of A + 32 of B per thread
    float4 ra[4][2], rb[4][2];
    const float* pA = gA + kt * BKK;
    const float* pB = gB + kt * BKK;
    #pragma unroll
    for (int p = 0; p < 4; ++p) {
      const int r = crow + 64 * p;
      const float4* a4 = (const float4*)(pA + (size_t)r * DIM + cg * 8);
      ra[p][0] = a4[0];
      ra[p][1] = a4[1];
      const float4* b4 = (const float4*)(pB + (size_t)r * DIM + cg * 8);
      rb[p][0] = b4[0];
      rb[p][1] = b4[1];
    }
    __syncthreads();   // previous tile's MFMA reads finished
    // ---- convert fp32 -> f16, accumulate ssq, write swizzled LDS
    #pragma unroll
    for (int p = 0; p < 4; ++p) {
      const int r   = crow + 64 * p;
      const int idx = r * BKK + ((cg * 8) ^ ((r & 7) << 3));
      {
        const float f0 = ra[p][0].x, f1 = ra[p][0].y, f2 = ra[p][0].z, f3 = ra[p][0].w;
        const float f4 = ra[p][1].x, f5 = ra[p][1].y, f6 = ra[p][1].z, f7 = ra[p][1].w;
        pssqA[p] += f0*f0 + f1*f1 + f2*f2 + f3*f3 + f4*f4 + f5*f5 + f6*f6 + f7*f7;
        f16x8 hv;
        hv[0] = (_Float16)f0; hv[1] = (_Float16)f1; hv[2] = (_Float16)f2; hv[3] = (_Float16)f3;
        hv[4] = (_Float16)f4; hv[5] = (_Float16)f5; hv[6] = (_Float16)f6; hv[7] = (_Float16)f7;
        *(f16x8*)&Ah[idx] = hv;
      }
      {
        const float f0 = rb[p][0].x, f1 = rb[p][0].y, f2 = rb[p][0].z, f3 = rb[p][0].w;
        const float f4 = rb[p][1].x, f5 = rb[p][1].y, f6 = rb[p][1].z, f7 = rb[p][1].w;
        pssqB[p] += f0*f0 + f1*f1 + f2*f2 + f3*f3 + f4*f4 + f5*f5 + f6*f6 + f7*f7;
        f16x8 hv;
        hv[0] = (_Float16)f0; hv[1] = (_Float16)f1; hv[2] = (_Float16)f2; hv[3] = (_Float16)f3;
        hv[4] = (_Float16)f4; hv[5] = (_Float16)f5; hv[6] = (_Float16)f6; hv[7] = (_Float16)f7;
        *(f16x8*)&Bh[idx] = hv;
      }
    }
    __syncthreads();
    // ---- MFMA on tile kt
    #pragma unroll
    for (int ks = 0; ks < 2; ++ks) {
      f16x8 af[4];
      #pragma unroll
      for (int fm = 0; fm < 4; ++fm) {
        const int r = wm * 64 + fm * 16 + li;
        const int g = ks * 4 + lh;
        af[fm] = *(const f16x8*)&Ah[r * BKK + ((g * 8) ^ ((r & 7) << 3))];
      }
      #pragma unroll
      for (int fn = 0; fn < 8; ++fn) {
        const int r = wn * 128 + fn * 16 + li;
        const int g = ks * 4 + lh;
        const f16x8 bf = *(const f16x8*)&Bh[r * BKK + ((g * 8) ^ ((r & 7) << 3))];
        #pragma unroll
        for (int fm = 0; fm < 4; ++fm)
          acc[fm][fn] = __builtin_amdgcn_mfma_f32_16x16x32_f16(af[fm], bf, acc[fm][fn], 0, 0, 0);
      }
    }
  }

  // ---- finalize sums of squares -> 1/norm
  #pragma unroll
  for (int p = 0; p < 4; ++p) {
    atomicAdd(&ssq1[crow + 64 * p], pssqA[p]);
    atomicAdd(&ssq2[crow + 64 * p], pssqB[p]);
  }
  __syncthreads();
  if (tid < 256) ssq1[tid] = 1.0f / sqrtf(ssq1[tid]);
  else           ssq2[tid - 256] = 1.0f / sqrtf(ssq2[tid - 256]);
  __syncthreads();

  const int n1 = len1[bb];
  const int n2 = len2[bb];

  // per-lane scale factors + validity
  float rn2v[8];
  bool  jv[8];
  #pragma unroll
  for (int fn = 0; fn < 8; ++fn) {
    const int j = wn * 128 + fn * 16 + li;
    rn2v[fn] = ssq2[j];
    jv[fn]   = (j < n2);
  }
  float rn1v[4][4];
  bool  iv[4][4];
  #pragma unroll
  for (int fm = 0; fm < 4; ++fm) {
    #pragma unroll
    for (int rg = 0; rg < 4; ++rg) {
      const int i = wm * 64 + fm * 16 + lh * 4 + rg;
      rn1v[fm][rg] = ssq1[i];
      iv[fm][rg]   = (i < n1);
    }
  }

  const float NEG = -3.402823466e38f;
  float rowm[4][4];   // max over valid j, per row slot (fm, rg)
  float colm[8];      // max over valid i, per col slot (fn)
  #pragma unroll
  for (int fm = 0; fm < 4; ++fm) {
    #pragma unroll
    for (int rg = 0; rg < 4; ++rg) rowm[fm][rg] = NEG;
  }
  #pragma unroll
  for (int fn = 0; fn < 8; ++fn) colm[fn] = NEG;

  #pragma unroll
  for (int fm = 0; fm < 4; ++fm) {
    #pragma unroll
    for (int fn = 0; fn < 8; ++fn) {
      #pragma unroll
      for (int rg = 0; rg < 4; ++rg) {
        const float v = acc[fm][fn][rg] * rn1v[fm][rg] * rn2v[fn];
        if (jv[fn] && v > rowm[fm][rg]) rowm[fm][rg] = v;
        if (iv[fm][rg] && v > colm[fn]) colm[fn] = v;
      }
    }
  }

  // reduce row maxima across the 16 lanes sharing lh (bits 0..3)
  #pragma unroll
  for (int m = 1; m <= 8; m <<= 1) {
    #pragma unroll
    for (int fm = 0; fm < 4; ++fm) {
      #pragma unroll
      for (int rg = 0; rg < 4; ++rg) {
        const float o = __shfl_xor(rowm[fm][rg], m, 64);
        rowm[fm][rg] = fmaxf(rowm[fm][rg], o);
      }
    }
  }
  // reduce col maxima across the 4 lane groups sharing li (bits 4..5)
  #pragma unroll
  for (int m = 16; m <= 32; m <<= 1) {
    #pragma unroll
    for (int fn = 0; fn < 8; ++fn) {
      const float o = __shfl_xor(colm[fn], m, 64);
      colm[fn] = fmaxf(colm[fn], o);
    }
  }

  if (li == 0) {
    #pragma unroll
    for (int fm = 0; fm < 4; ++fm) {
      #pragma unroll
      for (int rg = 0; rg < 4; ++rg)
        rowp[wm * 64 + fm * 16 + lh * 4 + rg][wn] = rowm[fm][rg];
    }
  }
  if (lh == 0) {
    #pragma unroll
    for (int fn = 0; fn < 8; ++fn)
      colp[wn * 128 + fn * 16 + li][wm] = colm[fn];
  }
  __syncthreads();

  float c1 = 0.f, c2 = 0.f;
  if (tid < 256) {
    const float rm = fmaxf(rowp[tid][0], rowp[tid][1]);
    if (tid < n1) c2 = rm;
    const float cm = fmaxf(fmaxf(colp[tid][0], colp[tid][1]),
                           fmaxf(colp[tid][2], colp[tid][3]));
    if (tid < n2) c1 = cm;
  }
  #pragma unroll
  for (int m = 1; m <= 32; m <<= 1) {
    c1 += __shfl_xor(c1, m, 64);
    c2 += __shfl_xor(c2, m, 64);
  }
  if (lane == 0) {
    redbuf[wid]     = c1;
    redbuf[8 + wid] = c2;
  }
  __syncthreads();
  if (tid == 0) {
    float s1s = 0.f, s2s = 0.f;
    #pragma unroll
    for (int i = 0; i < 8; ++i) { s1s += redbuf[i]; s2s += redbuf[8 + i]; }
    const float s1 = s1s / (float)n2;
    const float s2 = s2s / (float)n1;
    const float f1 = 2.0f * s1 * s2 / (s1 + s2);
    feat[bb * NLAYERS + nl] = f1;
  }
}

// ---------------------------------------------------------------------------
// Kernel 2: BatchNorm1d (training stats, biased var) over B=64 per layer,
// then linear head -> out[b].  One block, 4 waves (one wave per layer).
// ---------------------------------------------------------------------------
__global__ void bs_head(const float* __restrict__ feat, const float* __restrict__ w,
                        const float* __restrict__ bias, float* __restrict__ out) {
  __shared__ float lds[NLAYERS][BATCH];
  const int tid = threadIdx.x;
  const int nl  = tid >> 6;   // wave id = layer
  const int b   = tid & 63;   // lane = batch row

  const float x = feat[b * NLAYERS + nl];
  float s = x;
  #pragma unroll
  for (int m = 1; m <= 32; m <<= 1) s += __shfl_xor(s, m, 64);
  const float mean = s / 64.0f;
  const float d = x - mean;
  float v = d * d;
  #pragma unroll
  for (int m = 1; m <= 32; m <<= 1) v += __shfl_xor(v, m, 64);
  const float var = v / 64.0f;
  const float y = d / sqrtf(var + 1e-8f);

  lds[nl][b] = y * w[nl];
  __syncthreads();
  if (tid < 64)
    out[tid] = lds[0][tid] + lds[1][tid] + lds[2][tid] + lds[3][tid] + bias[0];
}

extern "C" void kernel_launch(void* const* d_in, const int* in_sizes, int n_in,
                              void* d_out, int out_size, void* d_ws, size_t ws_size,
                              hipStream_t stream) {
  const float* reps1 = (const float*)d_in[0];
  const float* reps2 = (const float*)d_in[1];
  const int*   len1  = (const int*)d_in[2];
  const int*   len2  = (const int*)d_in[3];
  const float* w     = (const float*)d_in[4];
  const float* bias  = (const float*)d_in[5];
  float* feat = (float*)d_ws;   // 64 x 4 floats

  bs_main<<<NLAYERS * BATCH, 512, 0, stream>>>(reps1, reps2, len1, len2, feat);
  bs_head<<<1, 256, 0, stream>>>(feat, w, bias, (float*)d_out);
}

// Round 2
// 146.656 us; speedup vs baseline: 1.1028x; 1.1028x over previous
//
#include <hip/hip_runtime.h>

#define NLAYERS 4
#define BATCH   64
#define LEN1    256
#define LEN2    256
#define DIM     1024
#define BKK     64
#define NKT     (DIM / BKK)   // 16 K-tiles

typedef _Float16 f16x8 __attribute__((ext_vector_type(8)));
typedef float    f32x4 __attribute__((ext_vector_type(4)));

// ---------------------------------------------------------------------------
// Kernel 1: one block per (nl, b).  Full 256x256 similarity tile via f16 MFMA
// (unnormalized dots), fp32 row sums-of-squares accumulated during staging,
// epilogue applies 1/(||r1_i|| ||r2_j||), masked max/mean -> F1 -> feat.
// Pipelined: double-buffered LDS, tile k+1 global loads issued before tile
// k's MFMA (in flight across compute), convert+ds_write after MFMA, ONE
// barrier per tile.
// ---------------------------------------------------------------------------
__global__ __launch_bounds__(512, 2)
void bs_main(const float* __restrict__ reps1, const float* __restrict__ reps2,
             const int* __restrict__ len1, const int* __restrict__ len2,
             float* __restrict__ feat) {
  __shared__ _Float16 Ah[2][LEN1 * BKK];   // 2 x 32 KB, XOR-swizzled
  __shared__ _Float16 Bh[2][LEN2 * BKK];   // 2 x 32 KB, XOR-swizzled
  __shared__ float ssq1[LEN1];
  __shared__ float ssq2[LEN2];
  __shared__ float rowp[LEN1][2];          // per-row max partials (by wn)
  __shared__ float colp[LEN2][4];          // per-col max partials (by wm)
  __shared__ float redbuf[16];

  const int bid = blockIdx.x;
  const int nl  = bid / BATCH;
  const int bb  = bid - nl * BATCH;
  const float* gA = reps1 + (size_t)(nl * BATCH + bb) * LEN1 * DIM;
  const float* gB = reps2 + (size_t)(nl * BATCH + bb) * LEN2 * DIM;

  const int tid  = threadIdx.x;
  const int lane = tid & 63;
  const int wid  = tid >> 6;     // 8 waves
  const int wm   = wid >> 1;     // 0..3  (M, 64 rows each)
  const int wn   = wid & 1;      // 0..1  (N, 128 cols each)
  const int li   = lane & 15;
  const int lh   = lane >> 4;

  if (tid < 256) ssq1[tid] = 0.0f;
  else           ssq2[tid - 256] = 0.0f;

  f32x4 acc[4][8];
  #pragma unroll
  for (int a = 0; a < 4; ++a) {
    #pragma unroll
    for (int c = 0; c < 8; ++c) acc[a][c] = 0.0f;
  }

  float pssqA[4] = {0.f, 0.f, 0.f, 0.f};
  float pssqB[4] = {0.f, 0.f, 0.f, 0.f};
  const int crow = tid >> 3;  // 0..63 : staging row group
  const int cg   = tid & 7;   // 0..7  : 8-float chunk within row

  float4 ra[4][2], rb[4][2];

  auto issue_loads = [&](int kt) {
    const float* pA = gA + kt * BKK;
    const float* pB = gB + kt * BKK;
    #pragma unroll
    for (int p = 0; p < 4; ++p) {
      const int r = crow + 64 * p;
      const float4* a4 = (const float4*)(pA + (size_t)r * DIM + cg * 8);
      ra[p][0] = a4[0];
      ra[p][1] = a4[1];
      const float4* b4 = (const float4*)(pB + (size_t)r * DIM + cg * 8);
      rb[p][0] = b4[0];
      rb[p][1] = b4[1];
    }
  };

  auto convert_write = [&](int buf) {
    #pragma unroll
    for (int p = 0; p < 4; ++p) {
      const int r   = crow + 64 * p;
      const int idx = r * BKK + ((cg * 8) ^ ((r & 7) << 3));
      {
        const float f0 = ra[p][0].x, f1 = ra[p][0].y, f2 = ra[p][0].z, f3 = ra[p][0].w;
        const float f4 = ra[p][1].x, f5 = ra[p][1].y, f6 = ra[p][1].z, f7 = ra[p][1].w;
        pssqA[p] += f0*f0 + f1*f1 + f2*f2 + f3*f3 + f4*f4 + f5*f5 + f6*f6 + f7*f7;
        f16x8 hv;
        hv[0] = (_Float16)f0; hv[1] = (_Float16)f1; hv[2] = (_Float16)f2; hv[3] = (_Float16)f3;
        hv[4] = (_Float16)f4; hv[5] = (_Float16)f5; hv[6] = (_Float16)f6; hv[7] = (_Float16)f7;
        *(f16x8*)&Ah[buf][idx] = hv;
      }
      {
        const float f0 = rb[p][0].x, f1 = rb[p][0].y, f2 = rb[p][0].z, f3 = rb[p][0].w;
        const float f4 = rb[p][1].x, f5 = rb[p][1].y, f6 = rb[p][1].z, f7 = rb[p][1].w;
        pssqB[p] += f0*f0 + f1*f1 + f2*f2 + f3*f3 + f4*f4 + f5*f5 + f6*f6 + f7*f7;
        f16x8 hv;
        hv[0] = (_Float16)f0; hv[1] = (_Float16)f1; hv[2] = (_Float16)f2; hv[3] = (_Float16)f3;
        hv[4] = (_Float16)f4; hv[5] = (_Float16)f5; hv[6] = (_Float16)f6; hv[7] = (_Float16)f7;
        *(f16x8*)&Bh[buf][idx] = hv;
      }
    }
  };

  // ---- prologue: tile 0 staged into buffer 0
  issue_loads(0);
  convert_write(0);
  __syncthreads();

  for (int kt = 0; kt < NKT; ++kt) {
    const int cur = kt & 1;
    const bool more = (kt + 1 < NKT);
    if (more) issue_loads(kt + 1);   // in flight across the MFMA phase

    // ---- MFMA on tile kt from buf[cur]
    const _Float16* AhC = Ah[cur];
    const _Float16* BhC = Bh[cur];
    #pragma unroll
    for (int ks = 0; ks < 2; ++ks) {
      f16x8 af[4];
      #pragma unroll
      for (int fm = 0; fm < 4; ++fm) {
        const int r = wm * 64 + fm * 16 + li;
        const int g = ks * 4 + lh;
        af[fm] = *(const f16x8*)&AhC[r * BKK + ((g * 8) ^ ((r & 7) << 3))];
      }
      #pragma unroll
      for (int fn = 0; fn < 8; ++fn) {
        const int r = wn * 128 + fn * 16 + li;
        const int g = ks * 4 + lh;
        const f16x8 bf = *(const f16x8*)&BhC[r * BKK + ((g * 8) ^ ((r & 7) << 3))];
        #pragma unroll
        for (int fm = 0; fm < 4; ++fm)
          acc[fm][fn] = __builtin_amdgcn_mfma_f32_16x16x32_f16(af[fm], bf, acc[fm][fn], 0, 0, 0);
      }
    }

    // ---- convert + write NEXT tile into the other buffer (waits on loads
    //      per-register; A-conversion overlaps B-load drain)
    if (more) convert_write(cur ^ 1);
    __syncthreads();
  }

  // ---- finalize sums of squares -> 1/norm
  #pragma unroll
  for (int p = 0; p < 4; ++p) {
    atomicAdd(&ssq1[crow + 64 * p], pssqA[p]);
    atomicAdd(&ssq2[crow + 64 * p], pssqB[p]);
  }
  __syncthreads();
  if (tid < 256) ssq1[tid] = 1.0f / sqrtf(ssq1[tid]);
  else           ssq2[tid - 256] = 1.0f / sqrtf(ssq2[tid - 256]);
  __syncthreads();

  const int n1 = len1[bb];
  const int n2 = len2[bb];

  float rn2v[8];
  bool  jv[8];
  #pragma unroll
  for (int fn = 0; fn < 8; ++fn) {
    const int j = wn * 128 + fn * 16 + li;
    rn2v[fn] = ssq2[j];
    jv[fn]   = (j < n2);
  }
  float rn1v[4][4];
  bool  iv[4][4];
  #pragma unroll
  for (int fm = 0; fm < 4; ++fm) {
    #pragma unroll
    for (int rg = 0; rg < 4; ++rg) {
      const int i = wm * 64 + fm * 16 + lh * 4 + rg;
      rn1v[fm][rg] = ssq1[i];
      iv[fm][rg]   = (i < n1);
    }
  }

  const float NEG = -3.402823466e38f;
  float rowm[4][4];
  float colm[8];
  #pragma unroll
  for (int fm = 0; fm < 4; ++fm) {
    #pragma unroll
    for (int rg = 0; rg < 4; ++rg) rowm[fm][rg] = NEG;
  }
  #pragma unroll
  for (int fn = 0; fn < 8; ++fn) colm[fn] = NEG;

  #pragma unroll
  for (int fm = 0; fm < 4; ++fm) {
    #pragma unroll
    for (int fn = 0; fn < 8; ++fn) {
      #pragma unroll
      for (int rg = 0; rg < 4; ++rg) {
        const float v = acc[fm][fn][rg] * rn1v[fm][rg] * rn2v[fn];
        if (jv[fn] && v > rowm[fm][rg]) rowm[fm][rg] = v;
        if (iv[fm][rg] && v > colm[fn]) colm[fn] = v;
      }
    }
  }

  #pragma unroll
  for (int m = 1; m <= 8; m <<= 1) {
    #pragma unroll
    for (int fm = 0; fm < 4; ++fm) {
      #pragma unroll
      for (int rg = 0; rg < 4; ++rg) {
        const float o = __shfl_xor(rowm[fm][rg], m, 64);
        rowm[fm][rg] = fmaxf(rowm[fm][rg], o);
      }
    }
  }
  #pragma unroll
  for (int m = 16; m <= 32; m <<= 1) {
    #pragma unroll
    for (int fn = 0; fn < 8; ++fn) {
      const float o = __shfl_xor(colm[fn], m, 64);
      colm[fn] = fmaxf(colm[fn], o);
    }
  }

  if (li == 0) {
    #pragma unroll
    for (int fm = 0; fm < 4; ++fm) {
      #pragma unroll
      for (int rg = 0; rg < 4; ++rg)
        rowp[wm * 64 + fm * 16 + lh * 4 + rg][wn] = rowm[fm][rg];
    }
  }
  if (lh == 0) {
    #pragma unroll
    for (int fn = 0; fn < 8; ++fn)
      colp[wn * 128 + fn * 16 + li][wm] = colm[fn];
  }
  __syncthreads();

  float c1 = 0.f, c2 = 0.f;
  if (tid < 256) {
    const float rm = fmaxf(rowp[tid][0], rowp[tid][1]);
    if (tid < n1) c2 = rm;
    const float cm = fmaxf(fmaxf(colp[tid][0], colp[tid][1]),
                           fmaxf(colp[tid][2], colp[tid][3]));
    if (tid < n2) c1 = cm;
  }
  #pragma unroll
  for (int m = 1; m <= 32; m <<= 1) {
    c1 += __shfl_xor(c1, m, 64);
    c2 += __shfl_xor(c2, m, 64);
  }
  if (lane == 0) {
    redbuf[wid]     = c1;
    redbuf[8 + wid] = c2;
  }
  __syncthreads();
  if (tid == 0) {
    float s1s = 0.f, s2s = 0.f;
    #pragma unroll
    for (int i = 0; i < 8; ++i) { s1s += redbuf[i]; s2s += redbuf[8 + i]; }
    const float s1 = s1s / (float)n2;
    const float s2 = s2s / (float)n1;
    const float f1 = 2.0f * s1 * s2 / (s1 + s2);
    feat[bb * NLAYERS + nl] = f1;
  }
}

// ---------------------------------------------------------------------------
// Kernel 2: BatchNorm1d (batch stats, biased var) + linear head -> out[b].
// ---------------------------------------------------------------------------
__global__ void bs_head(const float* __restrict__ feat, const float* __restrict__ w,
                        const float* __restrict__ bias, float* __restrict__ out) {
  __shared__ float lds[NLAYERS][BATCH];
  const int tid = threadIdx.x;
  const int nl  = tid >> 6;
  const int b   = tid & 63;

  const float x = feat[b * NLAYERS + nl];
  float s = x;
  #pragma unroll
  for (int m = 1; m <= 32; m <<= 1) s += __shfl_xor(s, m, 64);
  const float mean = s / 64.0f;
  const float d = x - mean;
  float v = d * d;
  #pragma unroll
  for (int m = 1; m <= 32; m <<= 1) v += __shfl_xor(v, m, 64);
  const float var = v / 64.0f;
  const float y = d / sqrtf(var + 1e-8f);

  lds[nl][b] = y * w[nl];
  __syncthreads();
  if (tid < 64)
    out[tid] = lds[0][tid] + lds[1][tid] + lds[2][tid] + lds[3][tid] + bias[0];
}

extern "C" void kernel_launch(void* const* d_in, const int* in_sizes, int n_in,
                              void* d_out, int out_size, void* d_ws, size_t ws_size,
                              hipStream_t stream) {
  const float* reps1 = (const float*)d_in[0];
  const float* reps2 = (const float*)d_in[1];
  const int*   len1  = (const int*)d_in[2];
  const int*   len2  = (const int*)d_in[3];
  const float* w     = (const float*)d_in[4];
  const float* bias  = (const float*)d_in[5];
  float* feat = (float*)d_ws;   // 64 x 4 floats

  bs_main<<<NLAYERS * BATCH, 512, 0, stream>>>(reps1, reps2, len1, len2, feat);
  bs_head<<<1, 256, 0, stream>>>(feat, w, bias, (float*)d_out);
}

// Round 3
// 126.066 us; speedup vs baseline: 1.2830x; 1.1633x over previous
//
#include <hip/hip_runtime.h>

#define NLAYERS 4
#define BATCH   64
#define LEN1    256
#define LEN2    256
#define DIM     1024
#define BKK     32
#define NKT     (DIM / BKK)   // 32 K-tiles
#define MHALF   128           // rows per block (M split in 2)
#define PITCH   40            // LDS row pitch in halfs (80 B) -> conflict-free

typedef _Float16 f16x8 __attribute__((ext_vector_type(8)));
typedef float    f32x4 __attribute__((ext_vector_type(4)));

__device__ __forceinline__ unsigned enc_f32(float v) {
  unsigned u = __float_as_uint(v);
  return (u & 0x80000000u) ? ~u : (u | 0x80000000u);
}
__device__ __forceinline__ float dec_f32(unsigned u) {
  return (u & 0x80000000u) ? __uint_as_float(u & 0x7fffffffu)
                           : __uint_as_float(~u);
}

// ---------------------------------------------------------------------------
// Kernel 1: grid 512 = 2 half-blocks (M=128) per (nl,b).  f16 MFMA on
// unnormalized dots, fp32 ssq on the fly, epilogue normalizes + reduces.
// Row-side (s2) complete in-block; col-maxes combined across the two halves
// via device atomicMax into workspace.  2 blocks/CU for memory overlap.
// ---------------------------------------------------------------------------
__global__ __launch_bounds__(512, 4)
void bs_main(const float* __restrict__ reps1, const float* __restrict__ reps2,
             const int* __restrict__ len1, const int* __restrict__ len2,
             unsigned* __restrict__ colmax, float* __restrict__ s2acc) {
  __shared__ _Float16 Ah[2][MHALF * PITCH];   // 2 x 10 KB
  __shared__ _Float16 Bh[2][LEN2 * PITCH];    // 2 x 20 KB
  __shared__ float ssq1[MHALF];
  __shared__ float ssq2[LEN2];
  __shared__ float rowp[MHALF][4];            // per-row max partials (by wn)
  __shared__ float colp[LEN2][2];             // per-col max partials (by wm)
  __shared__ float redbuf[8];

  const int bid  = blockIdx.x;
  // XCD pairing: bid and bid+8 share bid%8 -> same XCD -> B-slab L2 reuse
  const int pair = ((bid >> 4) << 3) | (bid & 7);   // 0..255 = nl*64+bb
  const int half = (bid >> 3) & 1;
  const int nl   = pair >> 6;
  const int bb   = pair & 63;
  const float* gA = reps1 + (size_t)pair * LEN1 * DIM + (size_t)half * MHALF * DIM;
  const float* gB = reps2 + (size_t)pair * LEN2 * DIM;

  const int tid  = threadIdx.x;
  const int lane = tid & 63;
  const int wid  = tid >> 6;     // 8 waves
  const int wm   = wid >> 2;     // 0..1  (M, 64 rows each)
  const int wn   = wid & 3;      // 0..3  (N, 64 cols each)
  const int li   = lane & 15;
  const int lh   = lane >> 4;

  if (tid < MHALF) ssq1[tid] = 0.0f;
  if (tid >= 128 && tid < 384) ssq2[tid - 128] = 0.0f;

  f32x4 acc[4][4];
  #pragma unroll
  for (int a = 0; a < 4; ++a)
    #pragma unroll
    for (int c = 0; c < 4; ++c) acc[a][c] = 0.0f;

  float pssqA = 0.f, pssqB = 0.f;
  const int rA = tid >> 2;            // 0..127, A row owned (all tiles)
  const int cA = (tid & 3) * 8;       // col group (8 floats)
  const int rB = tid >> 1;            // 0..255, B row owned
  const int cB = (tid & 1) * 16;      // col group (16 floats)

  float4 ra[2], rb[4];

  auto issue_loads = [&](int kt) {
    const float4* a4 = (const float4*)(gA + (size_t)rA * DIM + kt * BKK + cA);
    ra[0] = a4[0];  ra[1] = a4[1];
    const float4* b4 = (const float4*)(gB + (size_t)rB * DIM + kt * BKK + cB);
    rb[0] = b4[0];  rb[1] = b4[1];  rb[2] = b4[2];  rb[3] = b4[3];
  };

  auto convert_write = [&](int buf) {
    {
      const float f0 = ra[0].x, f1 = ra[0].y, f2 = ra[0].z, f3 = ra[0].w;
      const float f4 = ra[1].x, f5 = ra[1].y, f6 = ra[1].z, f7 = ra[1].w;
      pssqA += f0*f0 + f1*f1 + f2*f2 + f3*f3 + f4*f4 + f5*f5 + f6*f6 + f7*f7;
      f16x8 hv;
      hv[0] = (_Float16)f0; hv[1] = (_Float16)f1; hv[2] = (_Float16)f2; hv[3] = (_Float16)f3;
      hv[4] = (_Float16)f4; hv[5] = (_Float16)f5; hv[6] = (_Float16)f6; hv[7] = (_Float16)f7;
      *(f16x8*)&Ah[buf][rA * PITCH + cA] = hv;
    }
    #pragma unroll
    for (int q = 0; q < 2; ++q) {
      const float f0 = rb[2*q].x,   f1 = rb[2*q].y,   f2 = rb[2*q].z,   f3 = rb[2*q].w;
      const float f4 = rb[2*q+1].x, f5 = rb[2*q+1].y, f6 = rb[2*q+1].z, f7 = rb[2*q+1].w;
      pssqB += f0*f0 + f1*f1 + f2*f2 + f3*f3 + f4*f4 + f5*f5 + f6*f6 + f7*f7;
      f16x8 hv;
      hv[0] = (_Float16)f0; hv[1] = (_Float16)f1; hv[2] = (_Float16)f2; hv[3] = (_Float16)f3;
      hv[4] = (_Float16)f4; hv[5] = (_Float16)f5; hv[6] = (_Float16)f6; hv[7] = (_Float16)f7;
      *(f16x8*)&Bh[buf][rB * PITCH + cB + 8*q] = hv;
    }
  };

  issue_loads(0);
  convert_write(0);
  __syncthreads();

  for (int kt = 0; kt < NKT; ++kt) {
    const int cur = kt & 1;
    const bool more = (kt + 1 < NKT);
    if (more) issue_loads(kt + 1);   // in flight across MFMA phase

    const _Float16* AhC = Ah[cur];
    const _Float16* BhC = Bh[cur];
    f16x8 af[4];
    #pragma unroll
    for (int fm = 0; fm < 4; ++fm) {
      const int r = wm * 64 + fm * 16 + li;
      af[fm] = *(const f16x8*)&AhC[r * PITCH + lh * 8];
    }
    #pragma unroll
    for (int fn = 0; fn < 4; ++fn) {
      const int r = wn * 64 + fn * 16 + li;
      const f16x8 bf = *(const f16x8*)&BhC[r * PITCH + lh * 8];
      #pragma unroll
      for (int fm = 0; fm < 4; ++fm)
        acc[fm][fn] = __builtin_amdgcn_mfma_f32_16x16x32_f16(af[fm], bf, acc[fm][fn], 0, 0, 0);
    }

    if (more) convert_write(cur ^ 1);
    __syncthreads();
  }

  // ---- norms
  atomicAdd(&ssq1[rA], pssqA);
  atomicAdd(&ssq2[rB], pssqB);
  __syncthreads();
  if (tid < MHALF) ssq1[tid] = 1.0f / sqrtf(ssq1[tid]);
  if (tid >= 128 && tid < 384) ssq2[tid - 128] = 1.0f / sqrtf(ssq2[tid - 128]);
  __syncthreads();

  const int n1 = len1[bb];
  const int n2 = len2[bb];

  float rn2v[4];
  bool  jv[4];
  #pragma unroll
  for (int fn = 0; fn < 4; ++fn) {
    const int j = wn * 64 + fn * 16 + li;
    rn2v[fn] = ssq2[j];
    jv[fn]   = (j < n2);
  }
  float rn1v[4][4];
  bool  iv[4][4];
  #pragma unroll
  for (int fm = 0; fm < 4; ++fm)
    #pragma unroll
    for (int rg = 0; rg < 4; ++rg) {
      const int i = wm * 64 + fm * 16 + lh * 4 + rg;
      rn1v[fm][rg] = ssq1[i];
      iv[fm][rg]   = (half * MHALF + i) < n1;
    }

  const float NEG = -3.402823466e38f;
  float rowm[4][4];
  float colm[4];
  #pragma unroll
  for (int fm = 0; fm < 4; ++fm)
    #pragma unroll
    for (int rg = 0; rg < 4; ++rg) rowm[fm][rg] = NEG;
  #pragma unroll
  for (int fn = 0; fn < 4; ++fn) colm[fn] = NEG;

  #pragma unroll
  for (int fm = 0; fm < 4; ++fm)
    #pragma unroll
    for (int fn = 0; fn < 4; ++fn)
      #pragma unroll
      for (int rg = 0; rg < 4; ++rg) {
        const float v = acc[fm][fn][rg] * rn1v[fm][rg] * rn2v[fn];
        if (jv[fn] && v > rowm[fm][rg]) rowm[fm][rg] = v;
        if (iv[fm][rg] && v > colm[fn]) colm[fn] = v;
      }

  // row maxima: reduce across li (lane bits 0..3)
  #pragma unroll
  for (int m = 1; m <= 8; m <<= 1)
    #pragma unroll
    for (int fm = 0; fm < 4; ++fm)
      #pragma unroll
      for (int rg = 0; rg < 4; ++rg) {
        const float o = __shfl_xor(rowm[fm][rg], m, 64);
        rowm[fm][rg] = fmaxf(rowm[fm][rg], o);
      }
  // col maxima: reduce across lh (lane bits 4..5)
  #pragma unroll
  for (int m = 16; m <= 32; m <<= 1)
    #pragma unroll
    for (int fn = 0; fn < 4; ++fn) {
      const float o = __shfl_xor(colm[fn], m, 64);
      colm[fn] = fmaxf(colm[fn], o);
    }

  if (li == 0)
    #pragma unroll
    for (int fm = 0; fm < 4; ++fm)
      #pragma unroll
      for (int rg = 0; rg < 4; ++rg)
        rowp[wm * 64 + fm * 16 + lh * 4 + rg][wn] = rowm[fm][rg];
  if (lh == 0)
    #pragma unroll
    for (int fn = 0; fn < 4; ++fn)
      colp[wn * 64 + fn * 16 + li][wm] = colm[fn];
  __syncthreads();

  // ---- s2 partial: masked sum of row maxima (rows local to this half)
  float c2 = 0.f;
  if (tid < MHALF) {
    const float rm = fmaxf(fmaxf(rowp[tid][0], rowp[tid][1]),
                           fmaxf(rowp[tid][2], rowp[tid][3]));
    if (half * MHALF + tid < n1) c2 = rm;
  }
  #pragma unroll
  for (int m = 1; m <= 32; m <<= 1) c2 += __shfl_xor(c2, m, 64);
  if (lane == 0) redbuf[wid] = c2;

  // ---- col maxima -> device atomicMax (combined across the two halves)
  if (tid < LEN2) {
    const float cm = fmaxf(colp[tid][0], colp[tid][1]);
    atomicMax(&colmax[pair * LEN2 + tid], enc_f32(cm));
  }
  __syncthreads();
  if (tid == 0) {
    float s = 0.f;
    #pragma unroll
    for (int i = 0; i < 8; ++i) s += redbuf[i];
    atomicAdd(&s2acc[pair], s);
  }
}

// ---------------------------------------------------------------------------
// Kernel 2: combine col-maxes -> s1, read s2 -> F1 -> feat[b][nl]
// ---------------------------------------------------------------------------
__global__ void bs_combine(const unsigned* __restrict__ colmax,
                           const float* __restrict__ s2acc,
                           const int* __restrict__ len1, const int* __restrict__ len2,
                           float* __restrict__ feat) {
  __shared__ float part[4];
  const int p   = blockIdx.x;     // pair = nl*64+bb
  const int tid = threadIdx.x;    // 256 threads
  const int bb  = p & 63;
  const int nl  = p >> 6;
  const int n1  = len1[bb];
  const int n2  = len2[bb];

  float c = 0.f;
  if (tid < n2) c = dec_f32(colmax[p * LEN2 + tid]);
  #pragma unroll
  for (int m = 1; m <= 32; m <<= 1) c += __shfl_xor(c, m, 64);
  if ((tid & 63) == 0) part[tid >> 6] = c;
  __syncthreads();
  if (tid == 0) {
    const float s1 = (part[0] + part[1] + part[2] + part[3]) / (float)n2;
    const float s2 = s2acc[p] / (float)n1;
    feat[bb * NLAYERS + nl] = 2.0f * s1 * s2 / (s1 + s2);
  }
}

// ---------------------------------------------------------------------------
// Kernel 3: BatchNorm1d (batch stats, biased var) + linear head -> out[b]
// ---------------------------------------------------------------------------
__global__ void bs_head(const float* __restrict__ feat, const float* __restrict__ w,
                        const float* __restrict__ bias, float* __restrict__ out) {
  __shared__ float lds[NLAYERS][BATCH];
  const int tid = threadIdx.x;
  const int nl  = tid >> 6;
  const int b   = tid & 63;

  const float x = feat[b * NLAYERS + nl];
  float s = x;
  #pragma unroll
  for (int m = 1; m <= 32; m <<= 1) s += __shfl_xor(s, m, 64);
  const float mean = s / 64.0f;
  const float d = x - mean;
  float v = d * d;
  #pragma unroll
  for (int m = 1; m <= 32; m <<= 1) v += __shfl_xor(v, m, 64);
  const float var = v / 64.0f;
  const float y = d / sqrtf(var + 1e-8f);

  lds[nl][b] = y * w[nl];
  __syncthreads();
  if (tid < 64)
    out[tid] = lds[0][tid] + lds[1][tid] + lds[2][tid] + lds[3][tid] + bias[0];
}

extern "C" void kernel_launch(void* const* d_in, const int* in_sizes, int n_in,
                              void* d_out, int out_size, void* d_ws, size_t ws_size,
                              hipStream_t stream) {
  const float* reps1 = (const float*)d_in[0];
  const float* reps2 = (const float*)d_in[1];
  const int*   len1  = (const int*)d_in[2];
  const int*   len2  = (const int*)d_in[3];
  const float* w     = (const float*)d_in[4];
  const float* bias  = (const float*)d_in[5];

  unsigned* colmax = (unsigned*)d_ws;                          // 256*256 u32
  float*    s2acc  = (float*)((char*)d_ws + 256 * 256 * 4);    // 256 f32
  float*    feat   = s2acc + 256;                              // 256 f32

  // zero colmax (0 = encoded -inf) and s2acc each call (deterministic)
  hipMemsetAsync(d_ws, 0, 256 * 256 * 4 + 2 * 256 * 4, stream);

  bs_main<<<2 * NLAYERS * BATCH, 512, 0, stream>>>(reps1, reps2, len1, len2,
                                                   colmax, s2acc);
  bs_combine<<<NLAYERS * BATCH, 256, 0, stream>>>(colmax, s2acc, len1, len2, feat);
  bs_head<<<1, 256, 0, stream>>>(feat, w, bias, (float*)d_out);
}

// Round 4
// 113.052 us; speedup vs baseline: 1.4306x; 1.1151x over previous
//
#include <hip/hip_runtime.h>

#define NLAYERS 4
#define BATCH   64
#define LEN1    256
#define LEN2    256
#define DIM     1024
#define BKK     32
#define NKT     (DIM / BKK)   // 32 K-tiles
#define PITCH   40            // LDS row pitch in halfs (80 B = 5x16B, aligned, balanced banks)

typedef _Float16 f16x8 __attribute__((ext_vector_type(8)));
typedef float    f32x4 __attribute__((ext_vector_type(4)));

// ---------------------------------------------------------------------------
// Kernel 1: one 1024-thread block per (nl, b) — 16 waves in a 4x4 grid, each
// wave owns a 64x64 output sub-tile.  A and B each read from global exactly
// ONCE (536 MB logical total).  f16 MFMA on unnormalized dots, fp32 row
// sums-of-squares accumulated during staging, epilogue normalizes, masked
// max/mean -> F1 -> feat.  Double-buffered LDS, loads for tile k+1 issued
// before tile k's MFMA, convert+write after, ONE barrier per tile.
// ---------------------------------------------------------------------------
__global__ __launch_bounds__(1024, 4)
void bs_main(const float* __restrict__ reps1, const float* __restrict__ reps2,
             const int* __restrict__ len1, const int* __restrict__ len2,
             float* __restrict__ feat) {
  __shared__ _Float16 Ah[2][LEN1 * PITCH];   // 2 x 20 KB
  __shared__ _Float16 Bh[2][LEN2 * PITCH];   // 2 x 20 KB
  __shared__ float ssq1[LEN1];
  __shared__ float ssq2[LEN2];
  __shared__ float rowp[LEN1][4];            // per-row max partials (by wn)
  __shared__ float colp[LEN2][4];            // per-col max partials (by wm)
  __shared__ float redbuf[32];

  const int bid = blockIdx.x;
  const int nl  = bid >> 6;
  const int bb  = bid & 63;
  const float* gA = reps1 + (size_t)bid * LEN1 * DIM;
  const float* gB = reps2 + (size_t)bid * LEN2 * DIM;

  const int tid  = threadIdx.x;
  const int lane = tid & 63;
  const int wid  = tid >> 6;     // 16 waves
  const int wm   = wid >> 2;     // 0..3  (M, 64 rows each)
  const int wn   = wid & 3;      // 0..3  (N, 64 cols each)
  const int li   = lane & 15;
  const int lh   = lane >> 4;

  if (tid < 256)                  ssq1[tid] = 0.0f;
  else if (tid < 512)             ssq2[tid - 256] = 0.0f;

  f32x4 acc[4][4];
  #pragma unroll
  for (int a = 0; a < 4; ++a)
    #pragma unroll
    for (int c = 0; c < 4; ++c) acc[a][c] = 0.0f;

  float pssqA = 0.f, pssqB = 0.f;
  const int rS = tid >> 2;            // 0..255 : staged row (same for A and B)
  const int cS = (tid & 3) * 8;       // col group (8 floats)

  float4 ra[2], rb[2];

  auto issue_loads = [&](int kt) {
    const float4* a4 = (const float4*)(gA + (size_t)rS * DIM + kt * BKK + cS);
    ra[0] = a4[0];  ra[1] = a4[1];
    const float4* b4 = (const float4*)(gB + (size_t)rS * DIM + kt * BKK + cS);
    rb[0] = b4[0];  rb[1] = b4[1];
  };

  auto convert_write = [&](int buf) {
    const int idx = rS * PITCH + cS;   // 80B pitch: 16B-aligned, balanced banks
    {
      const float f0 = ra[0].x, f1 = ra[0].y, f2 = ra[0].z, f3 = ra[0].w;
      const float f4 = ra[1].x, f5 = ra[1].y, f6 = ra[1].z, f7 = ra[1].w;
      pssqA += f0*f0 + f1*f1 + f2*f2 + f3*f3 + f4*f4 + f5*f5 + f6*f6 + f7*f7;
      f16x8 hv;
      hv[0] = (_Float16)f0; hv[1] = (_Float16)f1; hv[2] = (_Float16)f2; hv[3] = (_Float16)f3;
      hv[4] = (_Float16)f4; hv[5] = (_Float16)f5; hv[6] = (_Float16)f6; hv[7] = (_Float16)f7;
      *(f16x8*)&Ah[buf][idx] = hv;
    }
    {
      const float f0 = rb[0].x, f1 = rb[0].y, f2 = rb[0].z, f3 = rb[0].w;
      const float f4 = rb[1].x, f5 = rb[1].y, f6 = rb[1].z, f7 = rb[1].w;
      pssqB += f0*f0 + f1*f1 + f2*f2 + f3*f3 + f4*f4 + f5*f5 + f6*f6 + f7*f7;
      f16x8 hv;
      hv[0] = (_Float16)f0; hv[1] = (_Float16)f1; hv[2] = (_Float16)f2; hv[3] = (_Float16)f3;
      hv[4] = (_Float16)f4; hv[5] = (_Float16)f5; hv[6] = (_Float16)f6; hv[7] = (_Float16)f7;
      *(f16x8*)&Bh[buf][idx] = hv;
    }
  };

  issue_loads(0);
  convert_write(0);
  __syncthreads();

  for (int kt = 0; kt < NKT; ++kt) {
    const int cur = kt & 1;
    const bool more = (kt + 1 < NKT);
    if (more) issue_loads(kt + 1);   // in flight across the MFMA phase

    const _Float16* AhC = Ah[cur];
    const _Float16* BhC = Bh[cur];
    f16x8 af[4];
    #pragma unroll
    for (int fm = 0; fm < 4; ++fm) {
      const int r = wm * 64 + fm * 16 + li;
      af[fm] = *(const f16x8*)&AhC[r * PITCH + lh * 8];
    }
    #pragma unroll
    for (int fn = 0; fn < 4; ++fn) {
      const int r = wn * 64 + fn * 16 + li;
      const f16x8 bf = *(const f16x8*)&BhC[r * PITCH + lh * 8];
      #pragma unroll
      for (int fm = 0; fm < 4; ++fm)
        acc[fm][fn] = __builtin_amdgcn_mfma_f32_16x16x32_f16(af[fm], bf, acc[fm][fn], 0, 0, 0);
    }

    if (more) convert_write(cur ^ 1);
    __syncthreads();
  }

  // ---- norms
  atomicAdd(&ssq1[rS], pssqA);
  atomicAdd(&ssq2[rS], pssqB);
  __syncthreads();
  if (tid < 256)       ssq1[tid] = 1.0f / sqrtf(ssq1[tid]);
  else if (tid < 512)  ssq2[tid - 256] = 1.0f / sqrtf(ssq2[tid - 256]);
  __syncthreads();

  const int n1 = len1[bb];
  const int n2 = len2[bb];

  float rn2v[4];
  bool  jv[4];
  #pragma unroll
  for (int fn = 0; fn < 4; ++fn) {
    const int j = wn * 64 + fn * 16 + li;
    rn2v[fn] = ssq2[j];
    jv[fn]   = (j < n2);
  }
  float rn1v[4][4];
  bool  iv[4][4];
  #pragma unroll
  for (int fm = 0; fm < 4; ++fm)
    #pragma unroll
    for (int rg = 0; rg < 4; ++rg) {
      const int i = wm * 64 + fm * 16 + lh * 4 + rg;
      rn1v[fm][rg] = ssq1[i];
      iv[fm][rg]   = (i < n1);
    }

  const float NEG = -3.402823466e38f;
  float rowm[4][4];
  float colm[4];
  #pragma unroll
  for (int fm = 0; fm < 4; ++fm)
    #pragma unroll
    for (int rg = 0; rg < 4; ++rg) rowm[fm][rg] = NEG;
  #pragma unroll
  for (int fn = 0; fn < 4; ++fn) colm[fn] = NEG;

  #pragma unroll
  for (int fm = 0; fm < 4; ++fm)
    #pragma unroll
    for (int fn = 0; fn < 4; ++fn)
      #pragma unroll
      for (int rg = 0; rg < 4; ++rg) {
        const float v = acc[fm][fn][rg] * rn1v[fm][rg] * rn2v[fn];
        if (jv[fn] && v > rowm[fm][rg]) rowm[fm][rg] = v;
        if (iv[fm][rg] && v > colm[fn]) colm[fn] = v;
      }

  // row maxima: reduce across li (lane bits 0..3)
  #pragma unroll
  for (int m = 1; m <= 8; m <<= 1)
    #pragma unroll
    for (int fm = 0; fm < 4; ++fm)
      #pragma unroll
      for (int rg = 0; rg < 4; ++rg) {
        const float o = __shfl_xor(rowm[fm][rg], m, 64);
        rowm[fm][rg] = fmaxf(rowm[fm][rg], o);
      }
  // col maxima: reduce across lh (lane bits 4..5)
  #pragma unroll
  for (int m = 16; m <= 32; m <<= 1)
    #pragma unroll
    for (int fn = 0; fn < 4; ++fn) {
      const float o = __shfl_xor(colm[fn], m, 64);
      colm[fn] = fmaxf(colm[fn], o);
    }

  if (li == 0)
    #pragma unroll
    for (int fm = 0; fm < 4; ++fm)
      #pragma unroll
      for (int rg = 0; rg < 4; ++rg)
        rowp[wm * 64 + fm * 16 + lh * 4 + rg][wn] = rowm[fm][rg];
  if (lh == 0)
    #pragma unroll
    for (int fn = 0; fn < 4; ++fn)
      colp[wn * 64 + fn * 16 + li][wm] = colm[fn];
  __syncthreads();

  float c1 = 0.f, c2 = 0.f;
  if (tid < 256) {
    const float rm = fmaxf(fmaxf(rowp[tid][0], rowp[tid][1]),
                           fmaxf(rowp[tid][2], rowp[tid][3]));
    if (tid < n1) c2 = rm;
    const float cm = fmaxf(fmaxf(colp[tid][0], colp[tid][1]),
                           fmaxf(colp[tid][2], colp[tid][3]));
    if (tid < n2) c1 = cm;
  }
  #pragma unroll
  for (int m = 1; m <= 32; m <<= 1) {
    c1 += __shfl_xor(c1, m, 64);
    c2 += __shfl_xor(c2, m, 64);
  }
  if (lane == 0) {
    redbuf[wid]      = c1;
    redbuf[16 + wid] = c2;
  }
  __syncthreads();
  if (tid == 0) {
    float s1s = 0.f, s2s = 0.f;
    #pragma unroll
    for (int i = 0; i < 16; ++i) { s1s += redbuf[i]; s2s += redbuf[16 + i]; }
    const float s1 = s1s / (float)n2;
    const float s2 = s2s / (float)n1;
    feat[bb * NLAYERS + nl] = 2.0f * s1 * s2 / (s1 + s2);
  }
}

// ---------------------------------------------------------------------------
// Kernel 2: BatchNorm1d (batch stats, biased var) + linear head -> out[b]
// ---------------------------------------------------------------------------
__global__ void bs_head(const float* __restrict__ feat, const float* __restrict__ w,
                        const float* __restrict__ bias, float* __restrict__ out) {
  __shared__ float lds[NLAYERS][BATCH];
  const int tid = threadIdx.x;
  const int nl  = tid >> 6;
  const int b   = tid & 63;

  const float x = feat[b * NLAYERS + nl];
  float s = x;
  #pragma unroll
  for (int m = 1; m <= 32; m <<= 1) s += __shfl_xor(s, m, 64);
  const float mean = s / 64.0f;
  const float d = x - mean;
  float v = d * d;
  #pragma unroll
  for (int m = 1; m <= 32; m <<= 1) v += __shfl_xor(v, m, 64);
  const float var = v / 64.0f;
  const float y = d / sqrtf(var + 1e-8f);

  lds[nl][b] = y * w[nl];
  __syncthreads();
  if (tid < 64)
    out[tid] = lds[0][tid] + lds[1][tid] + lds[2][tid] + lds[3][tid] + bias[0];
}

extern "C" void kernel_launch(void* const* d_in, const int* in_sizes, int n_in,
                              void* d_out, int out_size, void* d_ws, size_t ws_size,
                              hipStream_t stream) {
  const float* reps1 = (const float*)d_in[0];
  const float* reps2 = (const float*)d_in[1];
  const int*   len1  = (const int*)d_in[2];
  const int*   len2  = (const int*)d_in[3];
  const float* w     = (const float*)d_in[4];
  const float* bias  = (const float*)d_in[5];
  float* feat = (float*)d_ws;   // 256 floats

  bs_main<<<NLAYERS * BATCH, 1024, 0, stream>>>(reps1, reps2, len1, len2, feat);
  bs_head<<<1, 256, 0, stream>>>(feat, w, bias, (float*)d_out);
}